// Round 6
// baseline (91.417 us; speedup 1.0000x reference)
//
#include <hip/hip_runtime.h>

#define TLEN 1000000
#define YS 64
#define XS 50000
#define CHUNK 16
#define WARM 16
#define SPAN (CHUNK + WARM)                    // 32 steps/wave
#define NCHUNK ((TLEN + CHUNK - 1) / CHUNK)    // 62500
#define RPW 16                                 // chunks (MFMA rows) per wave
#define NW ((NCHUNK + RPW - 1) / RPW)          // 3907
#define WPB 4
#define NBLK ((NW + WPB - 1) / WPB)            // 977
#define BSCALE ((float)XS)                     // per-step scale ~1; cancels in normalize

typedef float f32x4 __attribute__((ext_vector_type(4)));
typedef short bf16x8 __attribute__((ext_vector_type(8)));
typedef unsigned int u32x4 __attribute__((ext_vector_type(4)));
typedef unsigned int u32x2 __attribute__((ext_vector_type(2)));

__device__ __forceinline__ unsigned cvtpk(float lo, float hi) {
  unsigned r;
  asm("v_cvt_pk_bf16_f32 %0, %1, %2" : "=v"(r) : "v"(lo), "v"(hi));
  return r;
}
__device__ __forceinline__ unsigned short f2bf_rne(float f) {
  unsigned u = __float_as_uint(f);
  unsigned r = (u + 0x7FFFu + ((u >> 16) & 1u)) >> 16;
  return (unsigned short)r;
}
__device__ __forceinline__ float bfu_lo(unsigned d) { return __uint_as_float(d << 16); }
__device__ __forceinline__ float bfu_hi(unsigned d) { return __uint_as_float(d & 0xffff0000u); }
__device__ __forceinline__ int clamp01(int t) {
  t = t < 0 ? 0 : t;
  return t > (TLEN - 1) ? (TLEN - 1) : t;
}

template <bool USE_BT>
__global__ __launch_bounds__(256, 4) void hmm_fwd(
    const int* __restrict__ x, const float* __restrict__ A,
    const float* __restrict__ pi, const float* __restrict__ bsrc,
    const unsigned* __restrict__ bpk, float* __restrict__ out)
{
  __shared__ __align__(16) float wlds[WPB][16][68];   // carry; 272B rows
  const int wslot = threadIdx.x >> 6;
  const int wv = blockIdx.x * WPB + wslot;
  const int lane = threadIdx.x & 63;
  if (wv >= NW) return;
  const int g = lane >> 4, c15 = lane & 15;   // MFMA A/C layout coords
  const int rr = lane >> 2, qq = lane & 3;    // store layout coords
  float (*wrow)[68] = wlds[wslot];

  // ---- B fragments: transition in single bf16 (RNE); Newton-refined rcp
  // downstream keeps total error ~1e-4.
  bf16x8 Bf[2][4];
#pragma unroll
  for (int h = 0; h < 2; h++)
#pragma unroll
    for (int nt = 0; nt < 4; nt++) {
      bf16x8 bh;
#pragma unroll
      for (int j = 0; j < 8; j++) {
        int k = 32 * h + g * 8 + j;
        int c = 16 * nt + c15;
        bh[j] = (short)f2bf_rne(A[k * YS + c]);
      }
      Bf[h][nt] = bh;
    }

  const int c0 = wv * RPW;

  // store-side per-lane time cursor (row rr): t = (c0+rr)*CHUNK - WARM + sabs
  int trow = (c0 + rr) * CHUNK - WARM;
  float* pout = out + (size_t)(trow < 0 ? 0 : trow) * YS + 4 * qq; // advanced manually
  // note: rows with trow<0 are skipped by guard; pointer advanced uniformly from t=0 base
  // so recompute exact base below instead:
  pout = out + (long)trow * YS + 4 * qq;

  // init carry (uniform; warm-up forgets it)
#pragma unroll
  for (int j = 0; j < 4; j++)
#pragma unroll
    for (int nt = 0; nt < 4; nt++)
      wrow[g * 4 + j][16 * nt + c15] = 1.0f;

  // chunk-0 exact fp32 init (C-layout lanes): o = pi * e0 * BSCALE
  float o[4];
  {
    int x0v = x[0];
#pragma unroll
    for (int nt = 0; nt < 4; nt++) {
      int c = 16 * nt + c15;
      o[nt] = pi[c] * bsrc[(size_t)c * XS + x0v] * BSCALE;
    }
  }
  const bool isw0 = (wv == 0);

  // packed-e loader: one dwordx2; d0 = bf16(c15|c15+16), d1 = bf16(c15+32|c15+48)
  auto eload2 = [&](int xt, unsigned& d0, unsigned& d1) {
    if (USE_BT) {
      u32x2 d = *(const u32x2*)(bpk + (size_t)(unsigned)xt * 32 + 2 * c15);
      d0 = d.x; d1 = d.y;
    } else {
      float e0 = bsrc[(size_t)(c15 +  0) * XS + xt] * BSCALE;
      float e1 = bsrc[(size_t)(c15 + 16) * XS + xt] * BSCALE;
      float e2 = bsrc[(size_t)(c15 + 32) * XS + xt] * BSCALE;
      float e3 = bsrc[(size_t)(c15 + 48) * XS + xt] * BSCALE;
      d0 = cvtpk(e0, e1); d1 = cvtpk(e2, e3);
    }
  };

  // ---- per-j time bases and 2-deep prefetch rings
  int tj0[4];
  unsigned er[2][4][2];   // e for steps s, s+1
  int xs[2][4];           // x for steps s+2, s+3
#pragma unroll
  for (int j = 0; j < 4; j++) {
    tj0[j] = (c0 + 4 * g + j) * CHUNK - WARM;
    eload2(x[clamp01(tj0[j] + 0)], er[0][j][0], er[0][j][1]);
    eload2(x[clamp01(tj0[j] + 1)], er[1][j][0], er[1][j][1]);
    xs[0][j] = x[clamp01(tj0[j] + 2)];
    xs[1][j] = x[clamp01(tj0[j] + 3)];
  }

  const f32x4 z4 = {0.f, 0.f, 0.f, 0.f};

  auto stepf = [&](int sabs, int ue) {
    // A-frags (carry) from LDS: row = c15, k = 8g+j (+32 for half 1)
    const f32x4* wr = (const f32x4*)&wrow[c15][0];
    f32x4 q0 = wr[2 * g];
    f32x4 q1 = wr[2 * g + 1];
    f32x4 q2 = wr[2 * g + 8];
    f32x4 q3 = wr[2 * g + 9];
    union { u32x4 u4; bf16x8 b; } ua0, ua1;
    ua0.u4 = (u32x4){cvtpk(q0.x, q0.y), cvtpk(q0.z, q0.w), cvtpk(q1.x, q1.y), cvtpk(q1.z, q1.w)};
    ua1.u4 = (u32x4){cvtpk(q2.x, q2.y), cvtpk(q2.z, q2.w), cvtpk(q3.x, q3.y), cvtpk(q3.z, q3.w)};
    bf16x8 a0 = ua0.b, a1 = ua1.b;

    f32x4 C[4];
#pragma unroll
    for (int nt = 0; nt < 4; nt++) {
      f32x4 c = __builtin_amdgcn_mfma_f32_16x16x32_bf16(a0, Bf[0][nt], z4, 0, 0, 0);
      c = __builtin_amdgcn_mfma_f32_16x16x32_bf16(a1, Bf[1][nt], c, 0, 0, 0);
      C[nt] = c;
    }

    // fold e into C (bf16 pairs)
#pragma unroll
    for (int j = 0; j < 4; j++) {
      unsigned d0 = er[ue][j][0], d1 = er[ue][j][1];
      C[0][j] *= bfu_lo(d0);
      C[1][j] *= bfu_hi(d0);
      C[2][j] *= bfu_lo(d1);
      C[3][j] *= bfu_hi(d1);
    }

    // chunk 0 (row 0 of wave 0): hold exact init until its t=0
    if (isw0 && sabs <= WARM) {
#pragma unroll
      for (int nt = 0; nt < 4; nt++)
        C[nt][0] = (lane < 16) ? o[nt] : C[nt][0];
    }

    // carry to LDS for next step (wave-private, in-order DS)
#pragma unroll
    for (int j = 0; j < 4; j++)
#pragma unroll
      for (int nt = 0; nt < 4; nt++)
        wrow[g * 4 + j][16 * nt + c15] = C[nt][j];

    // refills: e for step sabs+2 (x held 2 deep), x for step sabs+4
#pragma unroll
    for (int j = 0; j < 4; j++) {
      eload2(xs[ue][j], er[ue][j][0], er[ue][j][1]);
      xs[ue][j] = x[clamp01(tj0[j] + sabs + 4)];
    }

    // store path: read carry in store layout (lane = row rr, quad qq)
    if (sabs >= WARM) {
      f32x4 v0 = *(const f32x4*)&wrow[rr][ 0 + 4 * qq];
      f32x4 v1 = *(const f32x4*)&wrow[rr][16 + 4 * qq];
      f32x4 v2 = *(const f32x4*)&wrow[rr][32 + 4 * qq];
      f32x4 v3 = *(const f32x4*)&wrow[rr][48 + 4 * qq];
      f32x4 vs = (v0 + v1) + (v2 + v3);
      float s = (vs.x + vs.y) + (vs.z + vs.w);
      s += __shfl_xor(s, 1);
      s += __shfl_xor(s, 2);
      float r0 = __builtin_amdgcn_rcpf(s);
      float rs = r0 * fmaf(-s, r0, 2.0f);   // Newton: removes 2^-12 rcp floor
      if (trow < TLEN) {
        *(f32x4*)(pout +  0) = v0 * rs;
        *(f32x4*)(pout + 16) = v1 * rs;
        *(f32x4*)(pout + 32) = v2 * rs;
        *(f32x4*)(pout + 48) = v3 * rs;
      }
    }
    trow += 1;
    pout += YS;
  };

  for (int s = 0; s < SPAN; s += 2) {
    stepf(s + 0, 0);
    stepf(s + 1, 1);
  }
}

// transpose+pack b (YS x XS f32) -> bpk (XS x 32 dwords), lane-adjacent layout:
// slot s2 = 2*c15 + p; p=0 -> cols (c15, c15+16), p=1 -> cols (c15+32, c15+48)
__global__ __launch_bounds__(256) void pack_b(
    const float* __restrict__ b, unsigned* __restrict__ bpk)
{
  __shared__ float tile[64][65];
  int x0 = blockIdx.x << 6;
  int lane = threadIdx.x & 63;
  int w = threadIdx.x >> 6;
  int xg = x0 + lane;
#pragma unroll
  for (int yy = 0; yy < 64; yy += 4) {
    int y = yy + w;
    tile[y][lane] = (xg < XS) ? b[(size_t)y * XS + xg] * BSCALE : 0.f;
  }
  __syncthreads();
  int s2 = threadIdx.x & 31;          // dword slot 0..31
  int xo = threadIdx.x >> 5;          // 0..7
  int c15 = s2 >> 1, p = s2 & 1;
  int colA = c15 + 32 * p, colB = colA + 16;
#pragma unroll
  for (int pass = 0; pass < 8; pass++) {
    int xl = pass * 8 + xo;
    int xcur = x0 + xl;
    if (xcur < XS)
      bpk[(size_t)xcur * 32 + s2] = cvtpk(tile[colA][xl], tile[colB][xl]);
  }
}

extern "C" void kernel_launch(void* const* d_in, const int* in_sizes, int n_in,
                              void* d_out, int out_size, void* d_ws, size_t ws_size,
                              hipStream_t stream)
{
  const int*   x  = (const int*)d_in[0];
  const float* A  = (const float*)d_in[1];
  const float* b  = (const float*)d_in[2];
  const float* pi = (const float*)d_in[3];
  float* out = (float*)d_out;

  const size_t bpk_bytes = (size_t)XS * 32 * sizeof(unsigned);  // 6.4 MB

  if (ws_size >= bpk_bytes) {
    unsigned* bpk = (unsigned*)d_ws;
    int tblocks = (XS + 63) / 64;
    pack_b<<<tblocks, 256, 0, stream>>>(b, bpk);
    hmm_fwd<true><<<NBLK, 256, 0, stream>>>(x, A, pi, b, bpk, out);
  } else {
    hmm_fwd<false><<<NBLK, 256, 0, stream>>>(x, A, pi, b, nullptr, out);
  }
}